// Round 12
// baseline (277.606 us; speedup 1.0000x reference)
//
#include <hip/hip_runtime.h>
#include <hip/hip_bf16.h>

#define H 2048
#define K 1024
#define R 3
#define BB 8
#define S 2048

typedef __bf16 bf16x8 __attribute__((ext_vector_type(8)));
typedef float f32x4 __attribute__((ext_vector_type(4)));
typedef unsigned short ushort8 __attribute__((ext_vector_type(8)));

static __device__ __forceinline__ unsigned short f2bf(float f) {
    unsigned int u = __float_as_uint(f);
    u += 0x7FFFu + ((u >> 16) & 1u);   // round-to-nearest-even
    return (unsigned short)(u >> 16);
}

#define GLOAD_LDS16(g, l)                                                      \
    __builtin_amdgcn_global_load_lds(                                          \
        (const __attribute__((address_space(1))) void*)(g),                    \
        (__attribute__((address_space(3))) void*)(l), 16, 0, 0)

// -------- transpose+convert: in f32 [rows][cols] -> out bf16 [cols][rows] ----
__global__ __launch_bounds__(256) void tpose(const float* __restrict__ in,
                                             unsigned short* __restrict__ out,
                                             int rows, int cols) {
    __shared__ float tile[32][33];
    int rr = blockIdx.z;
    const float* ip = in + (size_t)rr * rows * cols;
    unsigned short* op = out + (size_t)rr * rows * cols;
    int x = blockIdx.x * 32 + threadIdx.x;
    int y0 = blockIdx.y * 32 + threadIdx.y;
#pragma unroll
    for (int j = 0; j < 32; j += 8)
        tile[threadIdx.y + j][threadIdx.x] = ip[(size_t)(y0 + j) * cols + x];
    __syncthreads();
    int ox = blockIdx.y * 32 + threadIdx.x;
    int oy0 = blockIdx.x * 32 + threadIdx.y;
#pragma unroll
    for (int j = 0; j < 32; j += 8)
        op[(size_t)(oy0 + j) * rows + ox] = f2bf(tile[threadIdx.x][threadIdx.y + j]);
}

// ==== 128x256 NT GEMM, BK=32, ring-3 24KB slots (72KB LDS -> 2 blocks/CU) ====
// r11 structure (best measured: 33% MfmaUtil, 0 conflicts, 2 blocks/CU).
// MODE 0 (GEMM1): A source is FP32 (hs) -- fused convert: af32(t+1) loaded as
//   loop-carried float4 pair one iter ahead (compiler auto-waits at cvt use),
//   cvt_pk'd to bf16 and ds_write_b128 to the SAME linear LDS dest the
//   gload_lds version used (frag reads unchanged). Gate vmcnt(4) forces only
//   B(t+1) (issue order B(t+1), af32(t+2), B(t+2)); lgkmcnt(0) before the
//   end barrier makes the A ds_write visible to other waves (cost ~0).
//   Epilogue: h = bf16 gelu(acc+bias).
// MODE 1 (GEMM2): exactly r11 (A bf16 via gload_lds, vmcnt(3) gate);
//   epilogue y = bf16(acc+bias+resid_f32) + per-block row stats -> Part.
template <int KC, int MODE>
__global__ __launch_bounds__(512, 4) void gemm_tlp(
    const void* __restrict__ Ain, const unsigned short* __restrict__ Bt,
    const int* __restrict__ role, const float* __restrict__ bias,
    const float* __restrict__ residf, void* __restrict__ Out,
    float2* __restrict__ Part, int N) {
    constexpr int NT = KC / 32;
    __shared__ char smem[73728];         // 3 x 24576 (A 8KB + B 16KB per slot)
    const int tid = threadIdx.x;
    const int wid = tid >> 6, lane = tid & 63;
    const int wm = wid >> 2, wn = wid & 3;
    const int lr = lane & 15, lc = lane >> 4;

    const int nx = N >> 8;               // N/256 n-tiles
    const int cpx = gridDim.x >> 3;
    const int orig = (blockIdx.x & 7) * cpx + (blockIdx.x >> 3);
    const int tn = orig % nx;
    const int tmz = orig / nx;
    const int tm = tmz & 15;             // S/128 = 16 m-tiles
    const int z = tmz >> 4;
    const int r = role[z];

    const char* Bb = (const char*)(Bt + ((size_t)r * N + (size_t)tn * 256) * KC);

    const int P16 = tid * 16;            // linear LDS byte offset, one 16B/thr
    const int srowA = P16 >> 6;          // A-region row (64B bf16 rows)
    const int sslot = ((P16 >> 4) & 3) ^ ((srowA >> 1) & 3);   // swizzled src

#define STGB(sb, kt, c)                                                        \
    GLOAD_LDS16(Bb + (size_t)((c) * 128 + srowA) * (KC * 2) + sslot * 16 +     \
                    (kt) * 64,                                                 \
                smem + (sb) + 8192 + (c) * 8192 + P16)

    // MODE 0: f32 A source (reg-staged); MODE 1: bf16 A via gload_lds
    const char* Ab4 = nullptr;           // f32 base (MODE 0)
    const char* Ab2 = nullptr;           // bf16 base (MODE 1)
    size_t sgAf = 0, sgA = 0;
    if (MODE == 0) {
        Ab4 = (const char*)((const float*)Ain + ((size_t)z * S + (size_t)tm * 128) * KC);
        sgAf = (size_t)srowA * (KC * 4) + sslot * 32;
    } else {
        Ab2 = (const char*)((const unsigned short*)Ain + ((size_t)z * S + (size_t)tm * 128) * KC);
        sgA = (size_t)srowA * (KC * 2) + sslot * 16;
    }

#define STGA_BF(sb, kt) GLOAD_LDS16(Ab2 + sgA + (kt) * 64, smem + (sb) + P16)
#define CVT_WRITE(sb, u0, u1)                                                  \
    do {                                                                       \
        bf16x8 pk_;                                                            \
        pk_[0] = (__bf16)(u0).x; pk_[1] = (__bf16)(u0).y;                      \
        pk_[2] = (__bf16)(u0).z; pk_[3] = (__bf16)(u0).w;                      \
        pk_[4] = (__bf16)(u1).x; pk_[5] = (__bf16)(u1).y;                      \
        pk_[6] = (__bf16)(u1).z; pk_[7] = (__bf16)(u1).w;                      \
        *(bf16x8*)(smem + (sb) + P16) = pk_;                                   \
    } while (0)

    float4 af0, af1;                     // loop-carried f32 A data (MODE 0)

    // ---------------- prologue ----------------
    if (MODE == 0) {
        float4 p0 = *(const float4*)(Ab4 + sgAf);
        float4 p1 = *(const float4*)(Ab4 + sgAf + 16);
        CVT_WRITE(0, p0, p1);                      // A(0) -> slot0
        STGB(0, 0, 0); STGB(0, 0, 1);              // B(0)
        af0 = *(const float4*)(Ab4 + sgAf + 128);  // A(1) -> regs
        af1 = *(const float4*)(Ab4 + sgAf + 144);
        STGB(24576, 1, 0); STGB(24576, 1, 1);      // B(1)
        asm volatile("s_waitcnt vmcnt(4)" ::: "memory");   // force B(0)
        asm volatile("s_waitcnt lgkmcnt(0)" ::: "memory"); // A(0) visible
    } else {
        STGA_BF(0, 0); STGB(0, 0, 0); STGB(0, 0, 1);
        STGA_BF(24576, 1); STGB(24576, 1, 0); STGB(24576, 1, 1);
        asm volatile("s_waitcnt vmcnt(3)" ::: "memory");
    }
    __builtin_amdgcn_s_barrier();

    f32x4 acc[4][4] = {};
    const int ck = (lc ^ ((lr >> 1) & 3)) << 4;   // swizzled 16B-slot
    const char* sm = smem;

    int sA = 0, sB = 24576, sC = 49152;  // slots t%3, (t+1)%3, (t+2)%3
#pragma unroll 1
    for (int t = 0; t < NT; ++t) {
        const bool pf = (t + 2) < NT;
        if (MODE == 0) {
            if (t + 1 < NT) CVT_WRITE(sB, af0, af1);         // A(t+1) -> LDS
            if (pf) {
                af0 = *(const float4*)(Ab4 + sgAf + (size_t)(t + 2) * 128);
                af1 = *(const float4*)(Ab4 + sgAf + (size_t)(t + 2) * 128 + 16);
                STGB(sC, t + 2, 0); STGB(sC, t + 2, 1);
            }
        } else {
            if (pf) { STGA_BF(sC, t + 2); STGB(sC, t + 2, 0); STGB(sC, t + 2, 1); }
        }
        bf16x8 a[4], b[4];
#pragma unroll
        for (int i = 0; i < 4; i++)
            a[i] = *(const bf16x8*)(sm + sA + ((wm * 64 + i * 16 + lr) << 6) + ck);
#pragma unroll
        for (int j = 0; j < 4; j++)
            b[j] = *(const bf16x8*)(sm + sA + 8192 + ((wn * 64 + j * 16 + lr) << 6) + ck);
        __builtin_amdgcn_s_setprio(1);
#pragma unroll
        for (int i = 0; i < 4; i++)
#pragma unroll
            for (int j = 0; j < 4; j++)
                acc[i][j] = __builtin_amdgcn_mfma_f32_16x16x32_bf16(a[i], b[j], acc[i][j], 0, 0, 0);
        __builtin_amdgcn_s_setprio(0);
        if (t < NT - 1) {
            if (MODE == 0) {
                if (pf) asm volatile("s_waitcnt vmcnt(4)" ::: "memory");
                else    asm volatile("s_waitcnt vmcnt(0)" ::: "memory");
                asm volatile("s_waitcnt lgkmcnt(0)" ::: "memory");
            } else {
                if (pf) asm volatile("s_waitcnt vmcnt(3)" ::: "memory");
                else    asm volatile("s_waitcnt vmcnt(0)" ::: "memory");
            }
            __builtin_amdgcn_s_barrier();
        }
        int tmp = sA; sA = sB; sB = sC; sC = tmp;
    }
#undef STGB
#undef STGA_BF
#undef CVT_WRITE

    // ---- epilogue ----
    const int base_m = tm * 128 + wm * 64;
    const int base_n = tn * 256 + wn * 64;
    float bn[4];
    const float* bp = bias + (size_t)r * N + base_n;
#pragma unroll
    for (int j = 0; j < 4; j++) bn[j] = bp[j * 16 + lr];

    if (MODE == 0) {
        unsigned short* o = (unsigned short*)Out;
#pragma unroll
        for (int i = 0; i < 4; i++) {
#pragma unroll
            for (int j = 0; j < 4; j++) {
#pragma unroll
                for (int q = 0; q < 4; q++) {
                    size_t grow = (size_t)z * S + base_m + i * 16 + lc * 4 + q;
                    int col = base_n + j * 16 + lr;
                    float x = acc[i][j][q] + bn[j];
                    float g = 0.5f * x * (1.0f + erff(x * 0.70710678118654752f));
                    o[grow * N + col] = f2bf(g);
                }
            }
        }
    } else {
        unsigned short* o = (unsigned short*)Out;     // y bf16
        float* pl = (float*)smem;                     // [8][128] partials
        __syncthreads();
#pragma unroll
        for (int i = 0; i < 4; i++) {
#pragma unroll
            for (int q = 0; q < 4; q++) {
                size_t grow = (size_t)z * S + base_m + i * 16 + lc * 4 + q;
                float s = 0.f, sq = 0.f;
#pragma unroll
                for (int j = 0; j < 4; j++) {
                    int col = base_n + j * 16 + lr;
                    float y = acc[i][j][q] + bn[j] + residf[grow * (size_t)N + col];
                    o[grow * (size_t)N + col] = f2bf(y);
                    s += y; sq += y * y;
                }
#pragma unroll
                for (int off = 1; off < 16; off <<= 1) {
                    s  += __shfl_xor(s, off);
                    sq += __shfl_xor(sq, off);
                }
                if (lr == 0) {
                    int rloc = wm * 64 + i * 16 + lc * 4 + q;   // 0..127
                    pl[wn * 128 + rloc] = s;
                    pl[512 + wn * 128 + rloc] = sq;
                }
            }
        }
        __syncthreads();
        if (tid < 128) {
            float s  = pl[tid] + pl[128 + tid] + pl[256 + tid] + pl[384 + tid];
            float sq = pl[512 + tid] + pl[640 + tid] + pl[768 + tid] + pl[896 + tid];
            size_t grow = (size_t)z * S + tm * 128 + tid;
            Part[(size_t)tn * (BB * S) + grow] = make_float2(s, sq);
        }
    }
}

// ------- LayerNorm: partials + y(bf16) -> out(f32), one block per row -------
__global__ __launch_bounds__(256) void ln2(const unsigned short* __restrict__ ybf,
                                           const float2* __restrict__ part,
                                           const int* __restrict__ role,
                                           const float* __restrict__ gamma,
                                           const float* __restrict__ beta,
                                           float* __restrict__ out) {
    int row = blockIdx.x;
    int z = row >> 11;                 // row / S
    int r = role[z];
    float s = 0.f, ss = 0.f;
#pragma unroll
    for (int nb = 0; nb < 8; nb++) {   // H/256 = 8 col-blocks
        float2 p = part[(size_t)nb * (BB * S) + row];
        s += p.x; ss += p.y;
    }
    float mean = s * (1.0f / H);
    float var = ss * (1.0f / H) - mean * mean;
    float rstd = rsqrtf(var + 1e-5f);
    int t = threadIdx.x;
    ushort8 yv = ((const ushort8*)(ybf + (size_t)row * H))[t];
    const float4* gp = (const float4*)(gamma + (size_t)r * H);
    const float4* bp = (const float4*)(beta + (size_t)r * H);
    float4 g0 = gp[2 * t], g1 = gp[2 * t + 1];
    float4 b0 = bp[2 * t], b1 = bp[2 * t + 1];
    float yo[8];
#pragma unroll
    for (int e = 0; e < 8; e++)
        yo[e] = (__uint_as_float(((unsigned)yv[e]) << 16) - mean) * rstd;
    float4 r0, r1;
    r0.x = yo[0] * g0.x + b0.x; r0.y = yo[1] * g0.y + b0.y;
    r0.z = yo[2] * g0.z + b0.z; r0.w = yo[3] * g0.w + b0.w;
    r1.x = yo[4] * g1.x + b1.x; r1.y = yo[5] * g1.y + b1.y;
    r1.z = yo[6] * g1.z + b1.z; r1.w = yo[7] * g1.w + b1.w;
    float4* op = (float4*)(out + (size_t)row * H);
    op[2 * t] = r0;
    op[2 * t + 1] = r1;
}

extern "C" void kernel_launch(void* const* d_in, const int* in_sizes, int n_in,
                              void* d_out, int out_size, void* d_ws, size_t ws_size,
                              hipStream_t stream) {
    const int* role = (const int*)d_in[0];
    const float* hs = (const float*)d_in[1];
    const float* Wd = (const float*)d_in[2];
    const float* bd = (const float*)d_in[3];
    const float* Wu = (const float*)d_in[4];
    const float* bu = (const float*)d_in[5];
    const float* gamma = (const float*)d_in[6];
    const float* beta = (const float*)d_in[7];
    float* out = (float*)d_out;

    char* ws = (char*)d_ws;
    // region A (64 MiB @0): y_bf (GEMM2 -> LN)
    unsigned short* y_bf = (unsigned short*)ws;
    // region B (12 MiB @64Mi): wd_t (tpose -> G1), then partials (G2 -> LN, 1 MiB)
    unsigned short* wd_t = (unsigned short*)(ws + 67108864);
    float2* part = (float2*)(ws + 67108864);
    // region C (12 MiB @76Mi): wu_t
    unsigned short* wu_t = (unsigned short*)(ws + 67108864 + 12582912);
    // region D (32 MiB @88Mi): h
    unsigned short* h_ws = (unsigned short*)(ws + 67108864 + 2 * 12582912);

    dim3 tb(32, 8);
    tpose<<<dim3(K / 32, H / 32, R), tb, 0, stream>>>(Wd, wd_t, H, K);
    tpose<<<dim3(H / 32, K / 32, R), tb, 0, stream>>>(Wu, wu_t, K, H);
    // GEMM1: h = gelu(hs(f32, fused cvt) x Wd^T + bd), bf16; 512 blocks
    gemm_tlp<H, 0><<<(K / 256) * 16 * BB, 512, 0, stream>>>(hs, wd_t, role, bd,
                                                            nullptr, h_ws, nullptr, K);
    // GEMM2: y = h x Wu^T + bu + hs(f32), bf16 + stats; 1024 blocks
    gemm_tlp<K, 1><<<(H / 256) * 16 * BB, 512, 0, stream>>>(h_ws, wu_t, role, bu,
                                                            hs, y_bf, part, H);
    ln2<<<BB * S, 256, 0, stream>>>(y_bf, part, role, gamma, beta, out);
}

// Round 13
// 272.058 us; speedup vs baseline: 1.0204x; 1.0204x over previous
//
#include <hip/hip_runtime.h>
#include <hip/hip_bf16.h>

#define H 2048
#define K 1024
#define R 3
#define BB 8
#define S 2048

typedef __bf16 bf16x8 __attribute__((ext_vector_type(8)));
typedef float f32x4 __attribute__((ext_vector_type(4)));
typedef unsigned short ushort8 __attribute__((ext_vector_type(8)));

static __device__ __forceinline__ unsigned short f2bf(float f) {
    unsigned int u = __float_as_uint(f);
    u += 0x7FFFu + ((u >> 16) & 1u);   // round-to-nearest-even
    return (unsigned short)(u >> 16);
}

#define GLOAD_LDS16(g, l)                                                      \
    __builtin_amdgcn_global_load_lds(                                          \
        (const __attribute__((address_space(1))) void*)(g),                    \
        (__attribute__((address_space(3))) void*)(l), 16, 0, 0)

// -------- transpose+convert: in f32 [rows][cols] -> out bf16 [cols][rows] ----
__global__ __launch_bounds__(256) void tpose(const float* __restrict__ in,
                                             unsigned short* __restrict__ out,
                                             int rows, int cols) {
    __shared__ float tile[32][33];
    int rr = blockIdx.z;
    const float* ip = in + (size_t)rr * rows * cols;
    unsigned short* op = out + (size_t)rr * rows * cols;
    int x = blockIdx.x * 32 + threadIdx.x;
    int y0 = blockIdx.y * 32 + threadIdx.y;
#pragma unroll
    for (int j = 0; j < 32; j += 8)
        tile[threadIdx.y + j][threadIdx.x] = ip[(size_t)(y0 + j) * cols + x];
    __syncthreads();
    int ox = blockIdx.y * 32 + threadIdx.x;
    int oy0 = blockIdx.x * 32 + threadIdx.y;
#pragma unroll
    for (int j = 0; j < 32; j += 8)
        op[(size_t)(oy0 + j) * rows + ox] = f2bf(tile[threadIdx.x][threadIdx.y + j]);
}

// ==== 128x256 NT GEMM, BK=32, ring-3 24KB slots (72KB LDS -> 2 blocks/CU) ====
// r11 structure (33% MfmaUtil, 0 conflicts, 2 blocks/CU).
// MODE 0 (GEMM1): A source FP32 (hs), fused convert with 2-ITER FLIGHT:
//   af = A(t+1) data (CVT_WRITE'd to LDS this iter), ag = A(t+2) data;
//   this iter loads A(t+3). The end-of-iter gate vmcnt(4) (leaves ag-load x2
//   + B(t+2) x2) forces B(t+1) AND A(t+2), so next iter's CVT_WRITE has its
//   data already resident -- no mid-phase stall (r12's 1-iter flight stalled
//   every iter: 19% MfmaUtil). lgkmcnt(0) before barrier makes the A ds_write
//   visible. Epilogue: h = bf16 gelu(acc+bias).
// MODE 1 (GEMM2): exactly r11 (A bf16 via gload_lds, vmcnt(3) gate);
//   epilogue y = bf16(acc+bias+resid_f32) + per-block row stats -> Part.
template <int KC, int MODE>
__global__ __launch_bounds__(512, 4) void gemm_tlp(
    const void* __restrict__ Ain, const unsigned short* __restrict__ Bt,
    const int* __restrict__ role, const float* __restrict__ bias,
    const float* __restrict__ residf, void* __restrict__ Out,
    float2* __restrict__ Part, int N) {
    constexpr int NT = KC / 32;
    __shared__ char smem[73728];         // 3 x 24576 (A 8KB + B 16KB per slot)
    const int tid = threadIdx.x;
    const int wid = tid >> 6, lane = tid & 63;
    const int wm = wid >> 2, wn = wid & 3;
    const int lr = lane & 15, lc = lane >> 4;

    const int nx = N >> 8;               // N/256 n-tiles
    const int cpx = gridDim.x >> 3;
    const int orig = (blockIdx.x & 7) * cpx + (blockIdx.x >> 3);
    const int tn = orig % nx;
    const int tmz = orig / nx;
    const int tm = tmz & 15;             // S/128 = 16 m-tiles
    const int z = tmz >> 4;
    const int r = role[z];

    const char* Bb = (const char*)(Bt + ((size_t)r * N + (size_t)tn * 256) * KC);

    const int P16 = tid * 16;            // linear LDS byte offset, one 16B/thr
    const int srowA = P16 >> 6;          // A-region row (64B bf16 rows)
    const int sslot = ((P16 >> 4) & 3) ^ ((srowA >> 1) & 3);   // swizzled src

#define STGB(sb, kt, c)                                                        \
    GLOAD_LDS16(Bb + (size_t)((c) * 128 + srowA) * (KC * 2) + sslot * 16 +     \
                    (kt) * 64,                                                 \
                smem + (sb) + 8192 + (c) * 8192 + P16)

    const char* Ab4 = nullptr;           // f32 base (MODE 0)
    const char* Ab2 = nullptr;           // bf16 base (MODE 1)
    size_t sgAf = 0, sgA = 0;
    if (MODE == 0) {
        Ab4 = (const char*)((const float*)Ain + ((size_t)z * S + (size_t)tm * 128) * KC);
        sgAf = (size_t)srowA * (KC * 4) + sslot * 32;
    } else {
        Ab2 = (const char*)((const unsigned short*)Ain + ((size_t)z * S + (size_t)tm * 128) * KC);
        sgA = (size_t)srowA * (KC * 2) + sslot * 16;
    }

#define STGA_BF(sb, kt) GLOAD_LDS16(Ab2 + sgA + (kt) * 64, smem + (sb) + P16)
#define CVT_WRITE(sb, u0, u1)                                                  \
    do {                                                                       \
        bf16x8 pk_;                                                            \
        pk_[0] = (__bf16)(u0).x; pk_[1] = (__bf16)(u0).y;                      \
        pk_[2] = (__bf16)(u0).z; pk_[3] = (__bf16)(u0).w;                      \
        pk_[4] = (__bf16)(u1).x; pk_[5] = (__bf16)(u1).y;                      \
        pk_[6] = (__bf16)(u1).z; pk_[7] = (__bf16)(u1).w;                      \
        *(bf16x8*)(smem + (sb) + P16) = pk_;                                   \
    } while (0)

    float4 af0, af1, ag0, ag1;           // 2-deep loop-carried f32 A data

    // ---------------- prologue ----------------
    if (MODE == 0) {
        float4 p0 = *(const float4*)(Ab4 + sgAf);
        float4 p1 = *(const float4*)(Ab4 + sgAf + 16);
        CVT_WRITE(0, p0, p1);                      // A(0) -> slot0
        STGB(0, 0, 0); STGB(0, 0, 1);              // B(0)
        af0 = *(const float4*)(Ab4 + sgAf + 128);  // A(1) -> regs
        af1 = *(const float4*)(Ab4 + sgAf + 144);
        ag0 = *(const float4*)(Ab4 + sgAf + 256);  // A(2) -> regs
        ag1 = *(const float4*)(Ab4 + sgAf + 272);
        STGB(24576, 1, 0); STGB(24576, 1, 1);      // B(1)
        asm volatile("s_waitcnt vmcnt(6)" ::: "memory");   // force B(0)
        asm volatile("s_waitcnt lgkmcnt(0)" ::: "memory"); // A(0) visible
    } else {
        STGA_BF(0, 0); STGB(0, 0, 0); STGB(0, 0, 1);
        STGA_BF(24576, 1); STGB(24576, 1, 0); STGB(24576, 1, 1);
        asm volatile("s_waitcnt vmcnt(3)" ::: "memory");
    }
    __builtin_amdgcn_s_barrier();

    f32x4 acc[4][4] = {};
    const int ck = (lc ^ ((lr >> 1) & 3)) << 4;   // swizzled 16B-slot
    const char* sm = smem;

    int sA = 0, sB = 24576, sC = 49152;  // slots t%3, (t+1)%3, (t+2)%3
#pragma unroll 1
    for (int t = 0; t < NT; ++t) {
        const bool pf2 = (t + 2) < NT, pf3 = (t + 3) < NT;
        if (MODE == 0) {
            if (t + 1 < NT) CVT_WRITE(sB, af0, af1);         // A(t+1) -> LDS
            af0 = ag0; af1 = ag1;                            // shift pipeline
            if (pf3) {
                ag0 = *(const float4*)(Ab4 + sgAf + (size_t)(t + 3) * 128);
                ag1 = *(const float4*)(Ab4 + sgAf + (size_t)(t + 3) * 128 + 16);
            }
            if (pf2) { STGB(sC, t + 2, 0); STGB(sC, t + 2, 1); }
        } else {
            if (pf2) { STGA_BF(sC, t + 2); STGB(sC, t + 2, 0); STGB(sC, t + 2, 1); }
        }
        bf16x8 a[4], b[4];
#pragma unroll
        for (int i = 0; i < 4; i++)
            a[i] = *(const bf16x8*)(sm + sA + ((wm * 64 + i * 16 + lr) << 6) + ck);
#pragma unroll
        for (int j = 0; j < 4; j++)
            b[j] = *(const bf16x8*)(sm + sA + 8192 + ((wn * 64 + j * 16 + lr) << 6) + ck);
        __builtin_amdgcn_s_setprio(1);
#pragma unroll
        for (int i = 0; i < 4; i++)
#pragma unroll
            for (int j = 0; j < 4; j++)
                acc[i][j] = __builtin_amdgcn_mfma_f32_16x16x32_bf16(a[i], b[j], acc[i][j], 0, 0, 0);
        __builtin_amdgcn_s_setprio(0);
        if (t < NT - 1) {
            if (MODE == 0) {
                // this iter issued: ag x2 (pf3) + B(t+2) x2 (pf2)
                if (pf3)      asm volatile("s_waitcnt vmcnt(4)" ::: "memory");
                else if (pf2) asm volatile("s_waitcnt vmcnt(2)" ::: "memory");
                else          asm volatile("s_waitcnt vmcnt(0)" ::: "memory");
                asm volatile("s_waitcnt lgkmcnt(0)" ::: "memory");
            } else {
                if (pf2) asm volatile("s_waitcnt vmcnt(3)" ::: "memory");
                else     asm volatile("s_waitcnt vmcnt(0)" ::: "memory");
            }
            __builtin_amdgcn_s_barrier();
        }
        int tmp = sA; sA = sB; sB = sC; sC = tmp;
    }
#undef STGB
#undef STGA_BF
#undef CVT_WRITE

    // ---- epilogue ----
    const int base_m = tm * 128 + wm * 64;
    const int base_n = tn * 256 + wn * 64;
    float bn[4];
    const float* bp = bias + (size_t)r * N + base_n;
#pragma unroll
    for (int j = 0; j < 4; j++) bn[j] = bp[j * 16 + lr];

    if (MODE == 0) {
        unsigned short* o = (unsigned short*)Out;
#pragma unroll
        for (int i = 0; i < 4; i++) {
#pragma unroll
            for (int j = 0; j < 4; j++) {
#pragma unroll
                for (int q = 0; q < 4; q++) {
                    size_t grow = (size_t)z * S + base_m + i * 16 + lc * 4 + q;
                    int col = base_n + j * 16 + lr;
                    float x = acc[i][j][q] + bn[j];
                    float g = 0.5f * x * (1.0f + erff(x * 0.70710678118654752f));
                    o[grow * N + col] = f2bf(g);
                }
            }
        }
    } else {
        unsigned short* o = (unsigned short*)Out;     // y bf16
        float* pl = (float*)smem;                     // [8][128] partials
        __syncthreads();
#pragma unroll
        for (int i = 0; i < 4; i++) {
#pragma unroll
            for (int q = 0; q < 4; q++) {
                size_t grow = (size_t)z * S + base_m + i * 16 + lc * 4 + q;
                float s = 0.f, sq = 0.f;
#pragma unroll
                for (int j = 0; j < 4; j++) {
                    int col = base_n + j * 16 + lr;
                    float y = acc[i][j][q] + bn[j] + residf[grow * (size_t)N + col];
                    o[grow * (size_t)N + col] = f2bf(y);
                    s += y; sq += y * y;
                }
#pragma unroll
                for (int off = 1; off < 16; off <<= 1) {
                    s  += __shfl_xor(s, off);
                    sq += __shfl_xor(sq, off);
                }
                if (lr == 0) {
                    int rloc = wm * 64 + i * 16 + lc * 4 + q;   // 0..127
                    pl[wn * 128 + rloc] = s;
                    pl[512 + wn * 128 + rloc] = sq;
                }
            }
        }
        __syncthreads();
        if (tid < 128) {
            float s  = pl[tid] + pl[128 + tid] + pl[256 + tid] + pl[384 + tid];
            float sq = pl[512 + tid] + pl[640 + tid] + pl[768 + tid] + pl[896 + tid];
            size_t grow = (size_t)z * S + tm * 128 + tid;
            Part[(size_t)tn * (BB * S) + grow] = make_float2(s, sq);
        }
    }
}

// ------- LayerNorm: partials + y(bf16) -> out(f32), one block per row -------
__global__ __launch_bounds__(256) void ln2(const unsigned short* __restrict__ ybf,
                                           const float2* __restrict__ part,
                                           const int* __restrict__ role,
                                           const float* __restrict__ gamma,
                                           const float* __restrict__ beta,
                                           float* __restrict__ out) {
    int row = blockIdx.x;
    int z = row >> 11;                 // row / S
    int r = role[z];
    float s = 0.f, ss = 0.f;
#pragma unroll
    for (int nb = 0; nb < 8; nb++) {   // H/256 = 8 col-blocks
        float2 p = part[(size_t)nb * (BB * S) + row];
        s += p.x; ss += p.y;
    }
    float mean = s * (1.0f / H);
    float var = ss * (1.0f / H) - mean * mean;
    float rstd = rsqrtf(var + 1e-5f);
    int t = threadIdx.x;
    ushort8 yv = ((const ushort8*)(ybf + (size_t)row * H))[t];
    const float4* gp = (const float4*)(gamma + (size_t)r * H);
    const float4* bp = (const float4*)(beta + (size_t)r * H);
    float4 g0 = gp[2 * t], g1 = gp[2 * t + 1];
    float4 b0 = bp[2 * t], b1 = bp[2 * t + 1];
    float yo[8];
#pragma unroll
    for (int e = 0; e < 8; e++)
        yo[e] = (__uint_as_float(((unsigned)yv[e]) << 16) - mean) * rstd;
    float4 r0, r1;
    r0.x = yo[0] * g0.x + b0.x; r0.y = yo[1] * g0.y + b0.y;
    r0.z = yo[2] * g0.z + b0.z; r0.w = yo[3] * g0.w + b0.w;
    r1.x = yo[4] * g1.x + b1.x; r1.y = yo[5] * g1.y + b1.y;
    r1.z = yo[6] * g1.z + b1.z; r1.w = yo[7] * g1.w + b1.w;
    float4* op = (float4*)(out + (size_t)row * H);
    op[2 * t] = r0;
    op[2 * t + 1] = r1;
}

extern "C" void kernel_launch(void* const* d_in, const int* in_sizes, int n_in,
                              void* d_out, int out_size, void* d_ws, size_t ws_size,
                              hipStream_t stream) {
    const int* role = (const int*)d_in[0];
    const float* hs = (const float*)d_in[1];
    const float* Wd = (const float*)d_in[2];
    const float* bd = (const float*)d_in[3];
    const float* Wu = (const float*)d_in[4];
    const float* bu = (const float*)d_in[5];
    const float* gamma = (const float*)d_in[6];
    const float* beta = (const float*)d_in[7];
    float* out = (float*)d_out;

    char* ws = (char*)d_ws;
    // region A (64 MiB @0): y_bf (GEMM2 -> LN)
    unsigned short* y_bf = (unsigned short*)ws;
    // region B (12 MiB @64Mi): wd_t (tpose -> G1), then partials (G2 -> LN, 1 MiB)
    unsigned short* wd_t = (unsigned short*)(ws + 67108864);
    float2* part = (float2*)(ws + 67108864);
    // region C (12 MiB @76Mi): wu_t
    unsigned short* wu_t = (unsigned short*)(ws + 67108864 + 12582912);
    // region D (32 MiB @88Mi): h
    unsigned short* h_ws = (unsigned short*)(ws + 67108864 + 2 * 12582912);

    dim3 tb(32, 8);
    tpose<<<dim3(K / 32, H / 32, R), tb, 0, stream>>>(Wd, wd_t, H, K);
    tpose<<<dim3(H / 32, K / 32, R), tb, 0, stream>>>(Wu, wu_t, K, H);
    // GEMM1: h = gelu(hs(f32, fused cvt 2-deep) x Wd^T + bd), bf16; 512 blocks
    gemm_tlp<H, 0><<<(K / 256) * 16 * BB, 512, 0, stream>>>(hs, wd_t, role, bd,
                                                            nullptr, h_ws, nullptr, K);
    // GEMM2: y = h x Wu^T + bu + hs(f32), bf16 + stats; 1024 blocks
    gemm_tlp<K, 1><<<(H / 256) * 16 * BB, 512, 0, stream>>>(h_ws, wu_t, role, bu,
                                                            hs, y_bf, part, H);
    ln2<<<BB * S, 256, 0, stream>>>(y_bf, part, role, gamma, beta, out);
}